// Round 12
// baseline (367.263 us; speedup 1.0000x reference)
//
#include <hip/hip_runtime.h>
#include <stdint.h>
#include <stddef.h>

// Problem constants
#define BB 4
#define SS 2048
#define EE 1024
#define HH 16
#define DD 64
#define MTOT (BB * SS)   // 8192

// softmax scale (1/sqrt(64)) * log2(e); folded into Q projection epilogue
#define SOFTMAX_C (0.125f * 1.44269504088896340736f)

using bf16x8 = __attribute__((ext_vector_type(8))) __bf16;
using f32x4  = __attribute__((ext_vector_type(4))) float;
using s16x4  = __attribute__((ext_vector_type(4))) short;   // 4 bf16 (2 VGPRs)

__device__ inline unsigned short f2bf(float f) {
    union { float f; uint32_t u; } v; v.f = f;
    uint32_t u = v.u;
    u += 0x7fffu + ((u >> 16) & 1u);   // round-to-nearest-even
    return (unsigned short)(u >> 16);
}

// async global->LDS, 16 B per lane; LDS dest must be wave-uniform base
__device__ inline void gld_lds16(const unsigned short* g, unsigned short* l) {
    __builtin_amdgcn_global_load_lds(
        (const __attribute__((address_space(1))) unsigned int*)g,
        (__attribute__((address_space(3))) unsigned int*)l,
        16, 0, 0);
}

// ---------------------------------------------------------------------------
// single merged cast: 3 activation tensors (NX each) + 4 weight tensors (NW)
// ---------------------------------------------------------------------------
__global__ __launch_bounds__(256) void cast_all(
    const float* __restrict__ s0, const float* __restrict__ s1,
    const float* __restrict__ s2, const float* __restrict__ s3,
    const float* __restrict__ s4, const float* __restrict__ s5,
    const float* __restrict__ s6,
    unsigned short* __restrict__ d0, unsigned short* __restrict__ d1,
    unsigned short* __restrict__ d2, unsigned short* __restrict__ d3,
    unsigned short* __restrict__ d4, unsigned short* __restrict__ d5,
    unsigned short* __restrict__ d6) {
    constexpr int NX4 = MTOT * EE / 4;   // 1<<21
    constexpr int NW4 = EE * EE / 4;     // 1<<18
    int i = blockIdx.x * 256 + threadIdx.x;
    const float* src; unsigned short* dst; int local;
    if (i < 3 * NX4) {                   // segment boundaries are x256 aligned
        int seg = i >> 21; local = i & (NX4 - 1);
        src = seg == 0 ? s0 : seg == 1 ? s1 : s2;
        dst = seg == 0 ? d0 : seg == 1 ? d1 : d2;
    } else {
        int j = i - 3 * NX4;
        int seg = j >> 18; local = j & (NW4 - 1);
        src = seg == 0 ? s3 : seg == 1 ? s4 : seg == 2 ? s5 : s6;
        dst = seg == 0 ? d3 : seg == 1 ? d4 : seg == 2 ? d5 : d6;
    }
    float4 f = ((const float4*)src)[local];
    ushort4 o;
    o.x = f2bf(f.x); o.y = f2bf(f.y); o.z = f2bf(f.z); o.w = f2bf(f.w);
    ((ushort4*)dst)[local] = o;
}

// ---------------------------------------------------------------------------
// NT GEMM core -- the VERIFIED single-buffered m97 pattern (barrier; async
// stage; barrier; compute). 32 KB LDS. NO launch-bounds coercion (r10:
// forcing 5 waves/EU spills the 64-VGPR accumulator -> 430 MB scratch).
// Module keeps r8's instantiation set {<0>,<3>,<1>} (rule #19: dropping <1>
// in r9 perturbed gemm_qkv regalloc to 108 VGPR and cost a block/CU).
// C[m,n] = (sum_k A[m,k] * W[n,k] + bias) * oscale
// MODE 0: bias[n]; bf16 row-major [8192,1024]  (Q,K projections)
// MODE 1: bias[n]; fp32 [8192,1024] direct     (unlaunched, codegen anchor)
// MODE 3: bias[m]; bf16 into [B,H,D,S]         (V proj transposed)
// ---------------------------------------------------------------------------
template <int MODE>
__device__ __forceinline__ void gemm_core(
    const unsigned short* __restrict__ A,
    const unsigned short* __restrict__ W,
    const float* __restrict__ bias,
    void* __restrict__ outp, float oscale,
    int m0, int n0, unsigned short* Smem) {

    const int tid  = threadIdx.x;
    const int lane = tid & 63;
    const int wid  = tid >> 6;
    const int wm   = wid >> 1;
    const int wn   = wid & 1;
    const int quad = lane >> 4;
    const int l16  = lane & 15;

    f32x4 acc[4][4];
#pragma unroll
    for (int i = 0; i < 4; i++)
#pragma unroll
        for (int j = 0; j < 4; j++) acc[i][j] = (f32x4){0.f, 0.f, 0.f, 0.f};

    const int lrow = lane >> 3;
    const int lcol = (lane & 7) * 8;
    const unsigned short* ga = A + (size_t)(m0 + wid * 32 + lrow) * 1024 + lcol;
    const unsigned short* gb = W + (size_t)(n0 + wid * 32 + lrow) * 1024 + lcol;
    unsigned short* la = Smem + wid * 2048;
    unsigned short* lb = la + 8192;

    for (int k0 = 0; k0 < 1024; k0 += 64) {
        __syncthreads();
#pragma unroll
        for (int c = 0; c < 4; c++) {
            gld_lds16(ga + (size_t)c * 8 * 1024 + k0, la + c * 512);
            gld_lds16(gb + (size_t)c * 8 * 1024 + k0, lb + c * 512);
        }
        __syncthreads();

        const unsigned short* As = Smem;
        const unsigned short* Bs = Smem + 8192;
#pragma unroll
        for (int kt = 0; kt < 2; kt++) {
            bf16x8 a[4], b[4];
#pragma unroll
            for (int mt = 0; mt < 4; mt++)
                a[mt] = *(const bf16x8*)(As + (wm * 64 + mt * 16 + l16) * 64 + kt * 32 + quad * 8);
#pragma unroll
            for (int nt = 0; nt < 4; nt++)
                b[nt] = *(const bf16x8*)(Bs + (wn * 64 + nt * 16 + l16) * 64 + kt * 32 + quad * 8);
#pragma unroll
            for (int mt = 0; mt < 4; mt++)
#pragma unroll
                for (int nt = 0; nt < 4; nt++)
                    acc[mt][nt] = __builtin_amdgcn_mfma_f32_16x16x32_bf16(
                        a[mt], b[nt], acc[mt][nt], 0, 0, 0);
        }
    }

    if (MODE == 0 || MODE == 3) {
        // bf16 epilogue: transpose through LDS in TWO 64-row passes (fits the
        // 32 KB Smem), then coalesced 16B stores. OS=136: odd-granule stride.
        constexpr int OS = 136;
        unsigned short* Os = Smem;         // 64*136*2 = 17.4 KB < 32 KB
#pragma unroll
        for (int p = 0; p < 2; ++p) {
            __syncthreads();               // guards K-loop reads / prev pass
            if (wm == p) {
#pragma unroll
                for (int mt = 0; mt < 4; mt++)
#pragma unroll
                    for (int nt = 0; nt < 4; nt++) {
                        int cl = wn * 64 + nt * 16 + l16;
                        float bvn = (MODE == 0) ? bias[n0 + cl] : 0.f;
#pragma unroll
                        for (int r = 0; r < 4; r++) {
                            int rl = mt * 16 + quad * 4 + r;   // 0..63
                            float bv = (MODE == 3) ? bias[m0 + p * 64 + rl] : bvn;
                            Os[rl * OS + cl] = f2bf((acc[mt][nt][r] + bv) * oscale);
                        }
                    }
            }
            __syncthreads();
            if (MODE == 0) {
                // row-major bf16 [8192][1024], rows m0+p*64 .. +63
#pragma unroll
                for (int i = 0; i < 4; i++) {
                    int c = tid + 256 * i;      // 1024 granules: 64 rows x 16
                    int row = c >> 4, g = c & 15;
                    *(uint4*)((unsigned short*)outp + (size_t)(m0 + p * 64 + row) * 1024 + n0 + g * 8)
                        = *(const uint4*)(Os + row * OS + g * 8);
                }
            } else {
                // [B,H,D,S]: rows are E-local (h,d), cols are seq-local
                const int bb = n0 >> 11, s0 = n0 & 2047;
#pragma unroll
                for (int i = 0; i < 4; i++) {
                    int c = tid + 256 * i;
                    int row = c >> 4, g = c & 15;
                    int er = m0 + p * 64 + row;
                    int hh = er >> 6, dd = er & 63;
                    *(uint4*)((unsigned short*)outp + (((size_t)(bb * HH + hh)) * DD + dd) * SS + s0 + g * 8)
                        = *(const uint4*)(Os + row * OS + g * 8);
                }
            }
        }
    } else {
        // MODE 1: fp32 row-major direct (64B/16-lane segments; verified r2)
#pragma unroll
        for (int mt = 0; mt < 4; mt++)
#pragma unroll
            for (int nt = 0; nt < 4; nt++) {
                int gcol = n0 + wn * 64 + nt * 16 + l16;
                float bvn = bias[gcol];
#pragma unroll
                for (int r = 0; r < 4; r++) {
                    int grow = m0 + wm * 64 + mt * 16 + quad * 4 + r;
                    ((float*)outp)[(size_t)grow * 1024 + gcol] =
                        (acc[mt][nt][r] + bvn) * oscale;
                }
            }
    }
}

// Q/K/V projections merged: grid (64, 8, 3) = 1536 blocks. x = m-tile so the
// 8 blocks sharing an A-panel (y=0..7) land on one XCD -> A-panel L2 reuse.
// z selects projection; V (z=2) swaps tile roles (m=E, n=seq).
__global__ __launch_bounds__(256) void gemm_qkv(
    const unsigned short* __restrict__ xq, const unsigned short* __restrict__ wq,
    const float* __restrict__ qb,
    const unsigned short* __restrict__ xk, const unsigned short* __restrict__ wk,
    const float* __restrict__ kb,
    const unsigned short* __restrict__ wv, const unsigned short* __restrict__ xv,
    const float* __restrict__ vb,
    unsigned short* __restrict__ qh, unsigned short* __restrict__ kh,
    unsigned short* __restrict__ vt) {
    __shared__ __align__(16) unsigned short Smem[16384];
    const int z = blockIdx.z;
    if (z == 0)
        gemm_core<0>(xq, wq, qb, qh, SOFTMAX_C, blockIdx.x * 128, blockIdx.y * 128, Smem);
    else if (z == 1)
        gemm_core<0>(xk, wk, kb, kh, 1.0f, blockIdx.x * 128, blockIdx.y * 128, Smem);
    else
        gemm_core<3>(wv, xv, vb, vt, 1.0f, blockIdx.y * 128, blockIdx.x * 128, Smem);
}

// r8-verbatim out-projection kernel. NOT LAUNCHED -- kept compiled so the
// module's gemm_core instantiation set matches r8 exactly (rule #19).
__global__ __launch_bounds__(256) void gemm_out(
    const unsigned short* __restrict__ A, const unsigned short* __restrict__ W,
    const float* __restrict__ bias, float* __restrict__ outp) {
    __shared__ __align__(16) unsigned short Smem[16384];
    gemm_core<1>(A, W, bias, outp, 1.0f, blockIdx.x * 128, blockIdx.y * 128, Smem);
}

// ---------------------------------------------------------------------------
// out-projection GEMM actually launched: 128m x 64n tiles, grid (64,16) =
// 1024 blocks = 4/CU. Same m97 sync pattern; B-tile 64 rows, wave tile
// 64x32, acc[4][2]. LDS 12 KB. fp32 direct stores.
// ---------------------------------------------------------------------------
__global__ __launch_bounds__(256) void gemm_out_n64(
    const unsigned short* __restrict__ A, const unsigned short* __restrict__ W,
    const float* __restrict__ bias, float* __restrict__ outp) {
    __shared__ __align__(16) unsigned short Smem[12288];  // A 8192 | B 4096

    const int tid  = threadIdx.x;
    const int lane = tid & 63;
    const int wid  = tid >> 6;
    const int wm   = wid >> 1;
    const int wn   = wid & 1;
    const int quad = lane >> 4;
    const int l16  = lane & 15;
    const int m0   = blockIdx.x * 128;
    const int n0   = blockIdx.y * 64;

    f32x4 acc[4][2];
#pragma unroll
    for (int i = 0; i < 4; i++)
#pragma unroll
        for (int j = 0; j < 2; j++) acc[i][j] = (f32x4){0.f, 0.f, 0.f, 0.f};

    const int lrow = lane >> 3;
    const int lcol = (lane & 7) * 8;
    const unsigned short* ga = A + (size_t)(m0 + wid * 32 + lrow) * 1024 + lcol;
    const unsigned short* gb = W + (size_t)(n0 + wid * 16 + lrow) * 1024 + lcol;
    unsigned short* la = Smem + wid * 2048;          // rows wid*32.. of A tile
    unsigned short* lb = Smem + 8192 + wid * 1024;   // rows wid*16.. of B tile

    for (int k0 = 0; k0 < 1024; k0 += 64) {
        __syncthreads();
#pragma unroll
        for (int c = 0; c < 4; c++)
            gld_lds16(ga + (size_t)c * 8 * 1024 + k0, la + c * 512);
#pragma unroll
        for (int c = 0; c < 2; c++)
            gld_lds16(gb + (size_t)c * 8 * 1024 + k0, lb + c * 512);
        __syncthreads();

        const unsigned short* As = Smem;
        const unsigned short* Bs = Smem + 8192;
#pragma unroll
        for (int kt = 0; kt < 2; kt++) {
            bf16x8 a[4], b[2];
#pragma unroll
            for (int mt = 0; mt < 4; mt++)
                a[mt] = *(const bf16x8*)(As + (wm * 64 + mt * 16 + l16) * 64 + kt * 32 + quad * 8);
#pragma unroll
            for (int nt = 0; nt < 2; nt++)
                b[nt] = *(const bf16x8*)(Bs + (wn * 32 + nt * 16 + l16) * 64 + kt * 32 + quad * 8);
#pragma unroll
            for (int mt = 0; mt < 4; mt++)
#pragma unroll
                for (int nt = 0; nt < 2; nt++)
                    acc[mt][nt] = __builtin_amdgcn_mfma_f32_16x16x32_bf16(
                        a[mt], b[nt], acc[mt][nt], 0, 0, 0);
        }
    }

    // fp32 row-major direct stores (verified r2 pattern)
#pragma unroll
    for (int mt = 0; mt < 4; mt++)
#pragma unroll
        for (int nt = 0; nt < 2; nt++) {
            int gcol = n0 + wn * 32 + nt * 16 + l16;
            float bvn = bias[gcol];
#pragma unroll
            for (int r = 0; r < 4; r++) {
                int grow = m0 + wm * 64 + mt * 16 + quad * 4 + r;
                outp[(size_t)grow * 1024 + gcol] = acc[mt][nt][r] + bvn;
            }
        }
}

// ---------------------------------------------------------------------------
// Flash attention v10: v9 with QBLK halved to 128 q-rows (grid 64 x 16 =
// 1024 blocks = 4 blocks/CU). v9's counters showed MfmaUtil 50 + VALUBusy 52
// with dur 2x the per-pipe work: barrier-lockstep phases + only 2 blocks/CU
// left the pipes alternating instead of overlapping. 4 independent blocks/CU
// (LDS 4 x 37.9 = 151.6 <= 160 KB; state halves so VGPR <= 64 naturally ->
// 8 waves/SIMD) lets one block's MFMA phase co-schedule with another's VALU
// phase (m114). Each wave owns ONE 16-row strip; COMPUTE is v9 minus the
// s-loop. Staging unchanged (512 threads cover the 64-row K/V tile in one
// pass). NO launch-bounds min-waves coercion (r10 lesson).
// ---------------------------------------------------------------------------
__global__ __launch_bounds__(512) void flash_attn10(
    const unsigned short* __restrict__ Qh,
    const unsigned short* __restrict__ Kh,
    const unsigned short* __restrict__ Vtg,
    unsigned short* __restrict__ attn) {
    constexpr int LSK = 72;                      // K tile row stride (shorts)
    constexpr int LSV = 76;                      // V tile row stride (shorts)
    constexpr int BUFSZ = 64 * LSK + 64 * LSV;   // 9472 shorts per buffer
    constexpr int NT = SS / 64;                  // 32 j-tiles
    __shared__ __align__(16) unsigned short Sh[2 * BUFSZ];  // 37888 B

    const int tid  = threadIdx.x;
    const int lane = tid & 63;
    const int w    = tid >> 6;            // 0..7
    const int quad = lane >> 4;
    const int l16  = lane & 15;
    const int bh   = blockIdx.x;          // b*H + h  (x so XCD = bh%8)
    const int q0   = blockIdx.y * 128;    // 128 q-rows per block
    const int b    = bh >> 4, h = bh & 15;
    const size_t baseqk = (size_t)b * SS * EE + h * 64;   // [B,S,E] + head col
    const size_t basev  = (size_t)bh * SS * DD;           // [B,H,D,S]

    // Q fragments (B-operand layout of 16x16x32), held all kernel:
    // wave w owns q-rows q0 + w*16 .. +15
    bf16x8 bq[2];
#pragma unroll
    for (int kt = 0; kt < 2; kt++)
        bq[kt] = *(const bf16x8*)(Qh + baseqk +
            (size_t)(q0 + w * 16 + l16) * EE + kt * 32 + quad * 8);

    f32x4 oT[4];
    float lsc = 0.f;                      // per-lane partial l (this quad's rows)
#pragma unroll
    for (int dt = 0; dt < 4; dt++) oT[dt] = (f32x4){0.f, 0.f, 0.f, 0.f};

    // staging geometry: 512 threads cover all 64 rows x 8-short chunks in one
    // pass (one K uint4 + one V uint4 per thread per tile)
    const int crow = tid >> 3;            // 0..63
    const int ccol = (tid & 7) * 8;       // 0..56
    uint4 kreg, vreg;

    auto LOADT = [&](int j0) {            // issue global loads (async)
        kreg = *(const uint4*)(Kh + baseqk + (size_t)(j0 + crow) * EE + ccol);
        vreg = *(const uint4*)(Vtg + basev + (size_t)crow * SS + j0 + ccol);
    };
    auto STORET = [&](unsigned short* KsD, unsigned short* VsD) {
        *(uint4*)(KsD + crow * LSK + ccol) = kreg;
        // V rows are 152 B apart (8 mod 16) -> two 8 B stores
        *(uint2*)(VsD + crow * LSV + ccol)     = uint2{vreg.x, vreg.y};
        *(uint2*)(VsD + crow * LSV + ccol + 4) = uint2{vreg.z, vreg.w};
    };

    auto COMPUTE = [&](const unsigned short* Ks, const unsigned short* Vs) {
        // S^T tiles: sacc[mt] = C[j_local = mt*16 + quad*4 + r][q = l16]
        f32x4 sacc[4];
#pragma unroll
        for (int mt = 0; mt < 4; mt++) sacc[mt] = (f32x4){0.f, 0.f, 0.f, 0.f};
        __builtin_amdgcn_s_setprio(1);
#pragma unroll
        for (int kt = 0; kt < 2; kt++) {
            bf16x8 ak[4];
#pragma unroll
            for (int mt = 0; mt < 4; mt++)
                ak[mt] = *(const bf16x8*)(Ks + (mt * 16 + l16) * LSK + kt * 32 + quad * 8);
#pragma unroll
            for (int mt = 0; mt < 4; mt++)
                sacc[mt] = __builtin_amdgcn_mfma_f32_16x16x32_bf16(
                    ak[mt], bq[kt], sacc[mt], 0, 0, 0);
        }
        __builtin_amdgcn_s_setprio(0);

        // p = exp2(s); truncate to bf16 (same values PV consumes), pack into
        // PV B-fragments, and accumulate l from the SAME truncated values.
        s16x4 bpf[4];
#pragma unroll
        for (int mt = 0; mt < 4; mt++) {
            union { float f; uint32_t u; } a0, a1, a2, a3;
            a0.f = __builtin_amdgcn_exp2f(sacc[mt][0]);
            a1.f = __builtin_amdgcn_exp2f(sacc[mt][1]);
            a2.f = __builtin_amdgcn_exp2f(sacc[mt][2]);
            a3.f = __builtin_amdgcn_exp2f(sacc[mt][3]);
            uint32_t u0 = a0.u & 0xFFFF0000u, u1 = a1.u & 0xFFFF0000u;
            uint32_t u2 = a2.u & 0xFFFF0000u, u3 = a3.u & 0xFFFF0000u;
            union { uint32_t w[2]; s16x4 v; } pk;
            pk.w[0] = (u0 >> 16) | u1;
            pk.w[1] = (u2 >> 16) | u3;
            bpf[mt] = pk.v;
            union { uint32_t u; float f; } t0{u0}, t1{u1}, t2{u2}, t3{u3};
            lsc += (t0.f + t1.f) + (t2.f + t3.f);
        }

        // PV: oT[dt] += V^T[d-tile][j-tile] x P[j-tile][q-strip]
        // A-frag: A[m=l16][k=quad*4+e] = Vs[(dt*16+l16)][mt*16+quad*4..+3]
        __builtin_amdgcn_s_setprio(1);
#pragma unroll
        for (int mt = 0; mt < 4; mt++) {
#pragma unroll
            for (int dt = 0; dt < 4; dt++) {
                s16x4 av = *(const s16x4*)(Vs + (dt * 16 + l16) * LSV + mt * 16 + quad * 4);
                oT[dt] = __builtin_amdgcn_mfma_f32_16x16x16bf16_1k(
                    av, bpf[mt], oT[dt], 0, 0, 0);
            }
        }
        __builtin_amdgcn_s_setprio(0);
    };

    // prologue: stage tile 0
    LOADT(0);
    STORET(Sh, Sh + 64 * LSK);
    __syncthreads();

    for (int jt = 0; jt < NT - 1; ++jt) {
        const int cur = jt & 1;
        const unsigned short* Ks = Sh + cur * BUFSZ;
        LOADT((jt + 1) * 64);                 // issue next tile's loads
        COMPUTE(Ks, Ks + 64 * LSK);           // latency hides under this
        unsigned short* Kn = Sh + (cur ^ 1) * BUFSZ;
        STORET(Kn, Kn + 64 * LSK);            // vmcnt wait inserted here
        __syncthreads();                      // one barrier per iter
    }
    {   // final tile: no prefetch
        const unsigned short* Ks = Sh + ((NT - 1) & 1) * BUFSZ;
        COMPUTE(Ks, Ks + 64 * LSK);
    }

    // l: this lane holds the sum over its quad's j-rows for q=l16; combine
    // the 4 quads (lanes l16 ^ 16 ^ 32) with one butterfly.
    float l = lsc;
    l += __shfl_xor(l, 16, 64);
    l += __shfl_xor(l, 32, 64);
    const float inv_l = 1.f / l;

    // epilogue: O^T (d rows, q cols) -> LDS transpose -> coalesced global.
    // 128 rows x 72 stride = 9216 shorts <= 2*BUFSZ (barrier-guarded).
    __syncthreads();  // all waves done reading Sh before overwrite
#pragma unroll
    for (int dt = 0; dt < 4; dt++)
#pragma unroll
        for (int r = 0; r < 4; r++)
            Sh[(w * 16 + l16) * LSK + dt * 16 + quad * 4 + r] =
                f2bf(oT[dt][r] * inv_l);
    __syncthreads();

#pragma unroll
    for (int i = 0; i < 2; i++) {
        int c = tid + 512 * i;              // 1024 chunks: 128 rows x 8
        int row = c >> 3, col8 = (c & 7) * 8;
        *(uint4*)(attn + ((size_t)b * SS + q0 + row) * EE + h * 64 + col8) =
            *(const uint4*)(Sh + row * LSK + col8);
    }
}

// ---------------------------------------------------------------------------
extern "C" void kernel_launch(void* const* d_in, const int* in_sizes, int n_in,
                              void* d_out, int out_size, void* d_ws, size_t ws_size,
                              hipStream_t stream) {
    (void)in_sizes; (void)n_in; (void)out_size; (void)ws_size;
    const float* q_in  = (const float*)d_in[0];
    const float* k_in  = (const float*)d_in[1];
    const float* v_in  = (const float*)d_in[2];
    const float* q_w   = (const float*)d_in[3];
    const float* q_b   = (const float*)d_in[4];
    const float* k_w   = (const float*)d_in[5];
    const float* k_b   = (const float*)d_in[6];
    const float* v_w   = (const float*)d_in[7];
    const float* v_b   = (const float*)d_in[8];
    const float* out_w = (const float*)d_in[9];
    const float* out_b = (const float*)d_in[10];

    const size_t NX = (size_t)MTOT * EE;   // 8388608 activation elements
    const size_t NW = (size_t)EE * EE;     // 1048576 weight elements

    unsigned short* xq = (unsigned short*)d_ws;
    unsigned short* xk = xq + NX;
    unsigned short* xv = xk + NX;
    unsigned short* wq = xv + NX;
    unsigned short* wk = wq + NW;
    unsigned short* wv = wk + NW;
    unsigned short* wo = wv + NW;
    unsigned short* qh = wo + NW;          // [B,S,E] bf16 row-major (pre-scaled)
    unsigned short* kh = qh + NX;          // [B,S,E] bf16 row-major
    unsigned short* vt = kh + NX;          // [B,H,D,S] bf16 (pre-transposed V)
    unsigned short* attn = vt + NX;        // [B,S,E] bf16

    // one launch for all 7 casts: 3*NX/4 + 4*NW/4 float4 granules
    const int total4 = (int)(3 * NX / 4 + 4 * NW / 4);
    cast_all<<<dim3(total4 / 256), 256, 0, stream>>>(
        q_in, k_in, v_in, q_w, k_w, v_w, out_w,
        xq, xk, xv, wq, wk, wv, wo);

    // merged Q/K/V projections; x = m-tile for XCD-affine A-panel reuse
    gemm_qkv<<<dim3(64, 8, 3), 256, 0, stream>>>(
        xq, wq, q_b, xk, wk, k_b, wv, xv, v_b, qh, kh, vt);

    // XCD-affine flash grid: x = bh (so XCD = bh%8), y = q-block (128 rows);
    // 1024 blocks = 4 blocks/CU for cross-block pipe overlap
    flash_attn10<<<dim3(BB * HH, SS / 128), 512, 0, stream>>>(qh, kh, vt, attn);

    // out projection: 128x64 tiles, 1024 blocks = 4/CU
    gemm_out_n64<<<dim3(64, 16), 256, 0, stream>>>(attn, wo, out_b, (float*)d_out);
}

// Round 13
// 345.330 us; speedup vs baseline: 1.0635x; 1.0635x over previous
//
#include <hip/hip_runtime.h>
#include <stdint.h>
#include <stddef.h>

// Problem constants
#define BB 4
#define SS 2048
#define EE 1024
#define HH 16
#define DD 64
#define MTOT (BB * SS)   // 8192

// softmax scale (1/sqrt(64)) * log2(e); folded into Q projection epilogue
#define SOFTMAX_C (0.125f * 1.44269504088896340736f)

using bf16x8 = __attribute__((ext_vector_type(8))) __bf16;
using f32x4  = __attribute__((ext_vector_type(4))) float;
using s16x4  = __attribute__((ext_vector_type(4))) short;   // 4 bf16 (2 VGPRs)

__device__ inline unsigned short f2bf(float f) {
    union { float f; uint32_t u; } v; v.f = f;
    uint32_t u = v.u;
    u += 0x7fffu + ((u >> 16) & 1u);   // round-to-nearest-even
    return (unsigned short)(u >> 16);
}

// async global->LDS, 16 B per lane; LDS dest must be wave-uniform base
__device__ inline void gld_lds16(const unsigned short* g, unsigned short* l) {
    __builtin_amdgcn_global_load_lds(
        (const __attribute__((address_space(1))) unsigned int*)g,
        (__attribute__((address_space(3))) unsigned int*)l,
        16, 0, 0);
}

// ---------------------------------------------------------------------------
// single merged cast: 3 activation tensors (NX each) + 4 weight tensors (NW)
// ---------------------------------------------------------------------------
__global__ __launch_bounds__(256) void cast_all(
    const float* __restrict__ s0, const float* __restrict__ s1,
    const float* __restrict__ s2, const float* __restrict__ s3,
    const float* __restrict__ s4, const float* __restrict__ s5,
    const float* __restrict__ s6,
    unsigned short* __restrict__ d0, unsigned short* __restrict__ d1,
    unsigned short* __restrict__ d2, unsigned short* __restrict__ d3,
    unsigned short* __restrict__ d4, unsigned short* __restrict__ d5,
    unsigned short* __restrict__ d6) {
    constexpr int NX4 = MTOT * EE / 4;   // 1<<21
    constexpr int NW4 = EE * EE / 4;     // 1<<18
    int i = blockIdx.x * 256 + threadIdx.x;
    const float* src; unsigned short* dst; int local;
    if (i < 3 * NX4) {                   // segment boundaries are x256 aligned
        int seg = i >> 21; local = i & (NX4 - 1);
        src = seg == 0 ? s0 : seg == 1 ? s1 : s2;
        dst = seg == 0 ? d0 : seg == 1 ? d1 : d2;
    } else {
        int j = i - 3 * NX4;
        int seg = j >> 18; local = j & (NW4 - 1);
        src = seg == 0 ? s3 : seg == 1 ? s4 : seg == 2 ? s5 : s6;
        dst = seg == 0 ? d3 : seg == 1 ? d4 : seg == 2 ? d5 : d6;
    }
    float4 f = ((const float4*)src)[local];
    ushort4 o;
    o.x = f2bf(f.x); o.y = f2bf(f.y); o.z = f2bf(f.z); o.w = f2bf(f.w);
    ((ushort4*)dst)[local] = o;
}

// ---------------------------------------------------------------------------
// NT GEMM core -- the VERIFIED single-buffered m97 pattern (barrier; async
// stage; barrier; compute). 32 KB LDS. NO launch-bounds coercion (r10:
// forcing 5 waves/EU spills the 64-VGPR accumulator -> 430 MB scratch).
// Module keeps r8's instantiation set {<0>,<3>,<1>} (rule #19: dropping <1>
// in r9 perturbed gemm_qkv regalloc to 108 VGPR and cost a block/CU).
// C[m,n] = (sum_k A[m,k] * W[n,k] + bias) * oscale
// MODE 0: bias[n]; bf16 row-major [8192,1024]  (Q,K projections)
// MODE 1: bias[n]; fp32 [8192,1024] direct     (unlaunched, codegen anchor)
// MODE 3: bias[m]; bf16 into [B,H,D,S]         (V proj transposed)
// ---------------------------------------------------------------------------
template <int MODE>
__device__ __forceinline__ void gemm_core(
    const unsigned short* __restrict__ A,
    const unsigned short* __restrict__ W,
    const float* __restrict__ bias,
    void* __restrict__ outp, float oscale,
    int m0, int n0, unsigned short* Smem) {

    const int tid  = threadIdx.x;
    const int lane = tid & 63;
    const int wid  = tid >> 6;
    const int wm   = wid >> 1;
    const int wn   = wid & 1;
    const int quad = lane >> 4;
    const int l16  = lane & 15;

    f32x4 acc[4][4];
#pragma unroll
    for (int i = 0; i < 4; i++)
#pragma unroll
        for (int j = 0; j < 4; j++) acc[i][j] = (f32x4){0.f, 0.f, 0.f, 0.f};

    const int lrow = lane >> 3;
    const int lcol = (lane & 7) * 8;
    const unsigned short* ga = A + (size_t)(m0 + wid * 32 + lrow) * 1024 + lcol;
    const unsigned short* gb = W + (size_t)(n0 + wid * 32 + lrow) * 1024 + lcol;
    unsigned short* la = Smem + wid * 2048;
    unsigned short* lb = la + 8192;

    for (int k0 = 0; k0 < 1024; k0 += 64) {
        __syncthreads();
#pragma unroll
        for (int c = 0; c < 4; c++) {
            gld_lds16(ga + (size_t)c * 8 * 1024 + k0, la + c * 512);
            gld_lds16(gb + (size_t)c * 8 * 1024 + k0, lb + c * 512);
        }
        __syncthreads();

        const unsigned short* As = Smem;
        const unsigned short* Bs = Smem + 8192;
#pragma unroll
        for (int kt = 0; kt < 2; kt++) {
            bf16x8 a[4], b[4];
#pragma unroll
            for (int mt = 0; mt < 4; mt++)
                a[mt] = *(const bf16x8*)(As + (wm * 64 + mt * 16 + l16) * 64 + kt * 32 + quad * 8);
#pragma unroll
            for (int nt = 0; nt < 4; nt++)
                b[nt] = *(const bf16x8*)(Bs + (wn * 64 + nt * 16 + l16) * 64 + kt * 32 + quad * 8);
#pragma unroll
            for (int mt = 0; mt < 4; mt++)
#pragma unroll
                for (int nt = 0; nt < 4; nt++)
                    acc[mt][nt] = __builtin_amdgcn_mfma_f32_16x16x32_bf16(
                        a[mt], b[nt], acc[mt][nt], 0, 0, 0);
        }
    }

    if (MODE == 0 || MODE == 3) {
        // bf16 epilogue: transpose through LDS in TWO 64-row passes (fits the
        // 32 KB Smem), then coalesced 16B stores. OS=136: odd-granule stride.
        constexpr int OS = 136;
        unsigned short* Os = Smem;         // 64*136*2 = 17.4 KB < 32 KB
#pragma unroll
        for (int p = 0; p < 2; ++p) {
            __syncthreads();               // guards K-loop reads / prev pass
            if (wm == p) {
#pragma unroll
                for (int mt = 0; mt < 4; mt++)
#pragma unroll
                    for (int nt = 0; nt < 4; nt++) {
                        int cl = wn * 64 + nt * 16 + l16;
                        float bvn = (MODE == 0) ? bias[n0 + cl] : 0.f;
#pragma unroll
                        for (int r = 0; r < 4; r++) {
                            int rl = mt * 16 + quad * 4 + r;   // 0..63
                            float bv = (MODE == 3) ? bias[m0 + p * 64 + rl] : bvn;
                            Os[rl * OS + cl] = f2bf((acc[mt][nt][r] + bv) * oscale);
                        }
                    }
            }
            __syncthreads();
            if (MODE == 0) {
                // row-major bf16 [8192][1024], rows m0+p*64 .. +63
#pragma unroll
                for (int i = 0; i < 4; i++) {
                    int c = tid + 256 * i;      // 1024 granules: 64 rows x 16
                    int row = c >> 4, g = c & 15;
                    *(uint4*)((unsigned short*)outp + (size_t)(m0 + p * 64 + row) * 1024 + n0 + g * 8)
                        = *(const uint4*)(Os + row * OS + g * 8);
                }
            } else {
                // [B,H,D,S]: rows are E-local (h,d), cols are seq-local
                const int bb = n0 >> 11, s0 = n0 & 2047;
#pragma unroll
                for (int i = 0; i < 4; i++) {
                    int c = tid + 256 * i;
                    int row = c >> 4, g = c & 15;
                    int er = m0 + p * 64 + row;
                    int hh = er >> 6, dd = er & 63;
                    *(uint4*)((unsigned short*)outp + (((size_t)(bb * HH + hh)) * DD + dd) * SS + s0 + g * 8)
                        = *(const uint4*)(Os + row * OS + g * 8);
                }
            }
        }
    } else {
        // MODE 1: fp32 row-major direct (64B/16-lane segments; verified r2)
#pragma unroll
        for (int mt = 0; mt < 4; mt++)
#pragma unroll
            for (int nt = 0; nt < 4; nt++) {
                int gcol = n0 + wn * 64 + nt * 16 + l16;
                float bvn = bias[gcol];
#pragma unroll
                for (int r = 0; r < 4; r++) {
                    int grow = m0 + wm * 64 + mt * 16 + quad * 4 + r;
                    ((float*)outp)[(size_t)grow * 1024 + gcol] =
                        (acc[mt][nt][r] + bvn) * oscale;
                }
            }
    }
}

// Q/K/V projections merged: grid (64, 8, 3) = 1536 blocks. x = m-tile so the
// 8 blocks sharing an A-panel (y=0..7) land on one XCD -> A-panel L2 reuse.
// z selects projection; V (z=2) swaps tile roles (m=E, n=seq).
__global__ __launch_bounds__(256) void gemm_qkv(
    const unsigned short* __restrict__ xq, const unsigned short* __restrict__ wq,
    const float* __restrict__ qb,
    const unsigned short* __restrict__ xk, const unsigned short* __restrict__ wk,
    const float* __restrict__ kb,
    const unsigned short* __restrict__ wv, const unsigned short* __restrict__ xv,
    const float* __restrict__ vb,
    unsigned short* __restrict__ qh, unsigned short* __restrict__ kh,
    unsigned short* __restrict__ vt) {
    __shared__ __align__(16) unsigned short Smem[16384];
    const int z = blockIdx.z;
    if (z == 0)
        gemm_core<0>(xq, wq, qb, qh, SOFTMAX_C, blockIdx.x * 128, blockIdx.y * 128, Smem);
    else if (z == 1)
        gemm_core<0>(xk, wk, kb, kh, 1.0f, blockIdx.x * 128, blockIdx.y * 128, Smem);
    else
        gemm_core<3>(wv, xv, vb, vt, 1.0f, blockIdx.y * 128, blockIdx.x * 128, Smem);
}

// r8-verbatim out-projection kernel. NOT LAUNCHED -- kept compiled so the
// module's gemm_core instantiation set matches r8 exactly (rule #19).
__global__ __launch_bounds__(256) void gemm_out(
    const unsigned short* __restrict__ A, const unsigned short* __restrict__ W,
    const float* __restrict__ bias, float* __restrict__ outp) {
    __shared__ __align__(16) unsigned short Smem[16384];
    gemm_core<1>(A, W, bias, outp, 1.0f, blockIdx.x * 128, blockIdx.y * 128, Smem);
}

// ---------------------------------------------------------------------------
// out-projection GEMM actually launched: 128m x 64n tiles, grid (64,16) =
// 1024 blocks = 4/CU. Same m97 sync pattern; B-tile 64 rows, wave tile
// 64x32, acc[4][2]. LDS 12 KB. fp32 direct stores.
// ---------------------------------------------------------------------------
__global__ __launch_bounds__(256) void gemm_out_n64(
    const unsigned short* __restrict__ A, const unsigned short* __restrict__ W,
    const float* __restrict__ bias, float* __restrict__ outp) {
    __shared__ __align__(16) unsigned short Smem[12288];  // A 8192 | B 4096

    const int tid  = threadIdx.x;
    const int lane = tid & 63;
    const int wid  = tid >> 6;
    const int wm   = wid >> 1;
    const int wn   = wid & 1;
    const int quad = lane >> 4;
    const int l16  = lane & 15;
    const int m0   = blockIdx.x * 128;
    const int n0   = blockIdx.y * 64;

    f32x4 acc[4][2];
#pragma unroll
    for (int i = 0; i < 4; i++)
#pragma unroll
        for (int j = 0; j < 2; j++) acc[i][j] = (f32x4){0.f, 0.f, 0.f, 0.f};

    const int lrow = lane >> 3;
    const int lcol = (lane & 7) * 8;
    const unsigned short* ga = A + (size_t)(m0 + wid * 32 + lrow) * 1024 + lcol;
    const unsigned short* gb = W + (size_t)(n0 + wid * 16 + lrow) * 1024 + lcol;
    unsigned short* la = Smem + wid * 2048;          // rows wid*32.. of A tile
    unsigned short* lb = Smem + 8192 + wid * 1024;   // rows wid*16.. of B tile

    for (int k0 = 0; k0 < 1024; k0 += 64) {
        __syncthreads();
#pragma unroll
        for (int c = 0; c < 4; c++)
            gld_lds16(ga + (size_t)c * 8 * 1024 + k0, la + c * 512);
#pragma unroll
        for (int c = 0; c < 2; c++)
            gld_lds16(gb + (size_t)c * 8 * 1024 + k0, lb + c * 512);
        __syncthreads();

        const unsigned short* As = Smem;
        const unsigned short* Bs = Smem + 8192;
#pragma unroll
        for (int kt = 0; kt < 2; kt++) {
            bf16x8 a[4], b[2];
#pragma unroll
            for (int mt = 0; mt < 4; mt++)
                a[mt] = *(const bf16x8*)(As + (wm * 64 + mt * 16 + l16) * 64 + kt * 32 + quad * 8);
#pragma unroll
            for (int nt = 0; nt < 2; nt++)
                b[nt] = *(const bf16x8*)(Bs + (wn * 32 + nt * 16 + l16) * 64 + kt * 32 + quad * 8);
#pragma unroll
            for (int mt = 0; mt < 4; mt++)
#pragma unroll
                for (int nt = 0; nt < 2; nt++)
                    acc[mt][nt] = __builtin_amdgcn_mfma_f32_16x16x32_bf16(
                        a[mt], b[nt], acc[mt][nt], 0, 0, 0);
        }
    }

    // fp32 row-major direct stores (verified r2 pattern)
#pragma unroll
    for (int mt = 0; mt < 4; mt++)
#pragma unroll
        for (int nt = 0; nt < 2; nt++) {
            int gcol = n0 + wn * 32 + nt * 16 + l16;
            float bvn = bias[gcol];
#pragma unroll
            for (int r = 0; r < 4; r++) {
                int grow = m0 + wm * 64 + mt * 16 + quad * 4 + r;
                outp[(size_t)grow * 1024 + gcol] = acc[mt][nt][r] + bvn;
            }
        }
}

// ---------------------------------------------------------------------------
// Flash attention v9 (VERIFIED r8/r11, 90.2 us): 8 waves / 512 threads /
// 256 q-rows per block; double-buffered LDS + async reg-staged K/V +
// zero-transform PV; VALU l-sum from the same truncated bf16 P-values;
// XCD-affine grid (x = bh so XCD = bh%8 -> K/V L2-resident per head).
// r12 showed QBLK=128 regresses (staging overhead per q-row doubles); the
// 256-row block is this structure's optimum.
// ---------------------------------------------------------------------------
__global__ __launch_bounds__(512) void flash_attn9(
    const unsigned short* __restrict__ Qh,
    const unsigned short* __restrict__ Kh,
    const unsigned short* __restrict__ Vtg,
    unsigned short* __restrict__ attn) {
    constexpr int LSK = 72;                      // K tile row stride (shorts)
    constexpr int LSV = 76;                      // V tile row stride (shorts)
    constexpr int BUFSZ = 64 * LSK + 64 * LSV;   // 9472 shorts per buffer
    constexpr int NT = SS / 64;                  // 32 j-tiles
    __shared__ __align__(16) unsigned short Sh[2 * BUFSZ];  // 37888 B

    const int tid  = threadIdx.x;
    const int lane = tid & 63;
    const int w    = tid >> 6;            // 0..7
    const int quad = lane >> 4;
    const int l16  = lane & 15;
    const int bh   = blockIdx.x;          // b*H + h  (x so XCD = bh%8)
    const int q0   = blockIdx.y * 256;    // 256 q-rows per block
    const int b    = bh >> 4, h = bh & 15;
    const size_t baseqk = (size_t)b * SS * EE + h * 64;   // [B,S,E] + head col
    const size_t basev  = (size_t)bh * SS * DD;           // [B,H,D,S]

    // Q fragments (B-operand layout of 16x16x32), held all kernel:
    bf16x8 bq[2][2];
#pragma unroll
    for (int s = 0; s < 2; s++)
#pragma unroll
        for (int kt = 0; kt < 2; kt++)
            bq[s][kt] = *(const bf16x8*)(Qh + baseqk +
                (size_t)(q0 + w * 32 + s * 16 + l16) * EE + kt * 32 + quad * 8);

    f32x4 oT[2][4];
    float lsc[2] = {0.f, 0.f};            // per-lane partial l (this quad's rows)
#pragma unroll
    for (int s = 0; s < 2; s++)
#pragma unroll
        for (int dt = 0; dt < 4; dt++) oT[s][dt] = (f32x4){0.f, 0.f, 0.f, 0.f};

    // staging geometry: 512 threads cover all 64 rows x 8-short chunks in one
    // pass (one K uint4 + one V uint4 per thread per tile)
    const int crow = tid >> 3;            // 0..63
    const int ccol = (tid & 7) * 8;       // 0..56
    uint4 kreg, vreg;

    auto LOADT = [&](int j0) {            // issue global loads (async)
        kreg = *(const uint4*)(Kh + baseqk + (size_t)(j0 + crow) * EE + ccol);
        vreg = *(const uint4*)(Vtg + basev + (size_t)crow * SS + j0 + ccol);
    };
    auto STORET = [&](unsigned short* KsD, unsigned short* VsD) {
        *(uint4*)(KsD + crow * LSK + ccol) = kreg;
        // V rows are 152 B apart (8 mod 16) -> two 8 B stores
        *(uint2*)(VsD + crow * LSV + ccol)     = uint2{vreg.x, vreg.y};
        *(uint2*)(VsD + crow * LSV + ccol + 4) = uint2{vreg.z, vreg.w};
    };

    auto COMPUTE = [&](const unsigned short* Ks, const unsigned short* Vs) {
        // S^T tiles: sacc[s][mt] = C[j_local = mt*16 + quad*4 + r][q = l16]
        f32x4 sacc[2][4];
#pragma unroll
        for (int s = 0; s < 2; s++)
#pragma unroll
            for (int mt = 0; mt < 4; mt++) sacc[s][mt] = (f32x4){0.f, 0.f, 0.f, 0.f};
        __builtin_amdgcn_s_setprio(1);
#pragma unroll
        for (int kt = 0; kt < 2; kt++) {
            bf16x8 ak[4];
#pragma unroll
            for (int mt = 0; mt < 4; mt++)
                ak[mt] = *(const bf16x8*)(Ks + (mt * 16 + l16) * LSK + kt * 32 + quad * 8);
#pragma unroll
            for (int s = 0; s < 2; s++)
#pragma unroll
                for (int mt = 0; mt < 4; mt++)
                    sacc[s][mt] = __builtin_amdgcn_mfma_f32_16x16x32_bf16(
                        ak[mt], bq[s][kt], sacc[s][mt], 0, 0, 0);
        }
        __builtin_amdgcn_s_setprio(0);

        // p = exp2(s); truncate to bf16 (same values PV consumes), pack into
        // PV B-fragments, and accumulate l from the SAME truncated values.
        s16x4 bpf[2][4];
#pragma unroll
        for (int s = 0; s < 2; s++) {
#pragma unroll
            for (int mt = 0; mt < 4; mt++) {
                union { float f; uint32_t u; } a0, a1, a2, a3;
                a0.f = __builtin_amdgcn_exp2f(sacc[s][mt][0]);
                a1.f = __builtin_amdgcn_exp2f(sacc[s][mt][1]);
                a2.f = __builtin_amdgcn_exp2f(sacc[s][mt][2]);
                a3.f = __builtin_amdgcn_exp2f(sacc[s][mt][3]);
                uint32_t u0 = a0.u & 0xFFFF0000u, u1 = a1.u & 0xFFFF0000u;
                uint32_t u2 = a2.u & 0xFFFF0000u, u3 = a3.u & 0xFFFF0000u;
                union { uint32_t w[2]; s16x4 v; } pk;
                pk.w[0] = (u0 >> 16) | u1;
                pk.w[1] = (u2 >> 16) | u3;
                bpf[s][mt] = pk.v;
                union { uint32_t u; float f; } t0{u0}, t1{u1}, t2{u2}, t3{u3};
                lsc[s] += (t0.f + t1.f) + (t2.f + t3.f);
            }
        }

        // PV: oT[s][dt] += V^T[d-tile][j-tile] x P[j-tile][q-strip]
        // A-frag: A[m=l16][k=quad*4+e] = Vs[(dt*16+l16)][mt*16+quad*4..+3]
        __builtin_amdgcn_s_setprio(1);
#pragma unroll
        for (int mt = 0; mt < 4; mt++) {
#pragma unroll
            for (int dt = 0; dt < 4; dt++) {
                s16x4 av = *(const s16x4*)(Vs + (dt * 16 + l16) * LSV + mt * 16 + quad * 4);
#pragma unroll
                for (int s = 0; s < 2; s++)
                    oT[s][dt] = __builtin_amdgcn_mfma_f32_16x16x16bf16_1k(
                        av, bpf[s][mt], oT[s][dt], 0, 0, 0);
            }
        }
        __builtin_amdgcn_s_setprio(0);
    };

    // prologue: stage tile 0
    LOADT(0);
    STORET(Sh, Sh + 64 * LSK);
    __syncthreads();

    for (int jt = 0; jt < NT - 1; ++jt) {
        const int cur = jt & 1;
        const unsigned short* Ks = Sh + cur * BUFSZ;
        LOADT((jt + 1) * 64);                 // issue next tile's loads
        COMPUTE(Ks, Ks + 64 * LSK);           // latency hides under this
        unsigned short* Kn = Sh + (cur ^ 1) * BUFSZ;
        STORET(Kn, Kn + 64 * LSK);            // vmcnt wait inserted here
        __syncthreads();                      // one barrier per iter
    }
    {   // final tile: no prefetch
        const unsigned short* Ks = Sh + ((NT - 1) & 1) * BUFSZ;
        COMPUTE(Ks, Ks + 64 * LSK);
    }

    // l: this lane holds the sum over its quad's j-rows for q=l16; combine
    // the 4 quads (lanes l16 ^ 16 ^ 32) with one butterfly.
    float inv_l[2];
#pragma unroll
    for (int s = 0; s < 2; s++) {
        float l = lsc[s];
        l += __shfl_xor(l, 16, 64);
        l += __shfl_xor(l, 32, 64);
        inv_l[s] = 1.f / l;
    }

    // epilogue: O^T (d rows, q cols) -> LDS transpose -> coalesced global.
    // 256 rows x 72 stride = 36864 shorts <= 2*BUFSZ (barrier-guarded).
    __syncthreads();  // all waves done reading Sh before overwrite
#pragma unroll
    for (int s = 0; s < 2; s++)
#pragma unroll
        for (int dt = 0; dt < 4; dt++)
#pragma unroll
            for (int r = 0; r < 4; r++)
                Sh[(w * 32 + s * 16 + l16) * LSK + dt * 16 + quad * 4 + r] =
                    f2bf(oT[s][dt][r] * inv_l[s]);
    __syncthreads();

#pragma unroll
    for (int i = 0; i < 4; i++) {
        int c = tid + 512 * i;              // 2048 chunks: 256 rows x 8
        int row = c >> 3, col8 = (c & 7) * 8;
        *(uint4*)(attn + ((size_t)b * SS + q0 + row) * EE + h * 64 + col8) =
            *(const uint4*)(Sh + row * LSK + col8);
    }
}

// ---------------------------------------------------------------------------
extern "C" void kernel_launch(void* const* d_in, const int* in_sizes, int n_in,
                              void* d_out, int out_size, void* d_ws, size_t ws_size,
                              hipStream_t stream) {
    (void)in_sizes; (void)n_in; (void)out_size; (void)ws_size;
    const float* q_in  = (const float*)d_in[0];
    const float* k_in  = (const float*)d_in[1];
    const float* v_in  = (const float*)d_in[2];
    const float* q_w   = (const float*)d_in[3];
    const float* q_b   = (const float*)d_in[4];
    const float* k_w   = (const float*)d_in[5];
    const float* k_b   = (const float*)d_in[6];
    const float* v_w   = (const float*)d_in[7];
    const float* v_b   = (const float*)d_in[8];
    const float* out_w = (const float*)d_in[9];
    const float* out_b = (const float*)d_in[10];

    const size_t NX = (size_t)MTOT * EE;   // 8388608 activation elements
    const size_t NW = (size_t)EE * EE;     // 1048576 weight elements

    unsigned short* xq = (unsigned short*)d_ws;
    unsigned short* xk = xq + NX;
    unsigned short* xv = xk + NX;
    unsigned short* wq = xv + NX;
    unsigned short* wk = wq + NW;
    unsigned short* wv = wk + NW;
    unsigned short* wo = wv + NW;
    unsigned short* qh = wo + NW;          // [B,S,E] bf16 row-major (pre-scaled)
    unsigned short* kh = qh + NX;          // [B,S,E] bf16 row-major
    unsigned short* vt = kh + NX;          // [B,H,D,S] bf16 (pre-transposed V)
    unsigned short* attn = vt + NX;        // [B,S,E] bf16

    // one launch for all 7 casts: 3*NX/4 + 4*NW/4 float4 granules
    const int total4 = (int)(3 * NX / 4 + 4 * NW / 4);
    cast_all<<<dim3(total4 / 256), 256, 0, stream>>>(
        q_in, k_in, v_in, q_w, k_w, v_w, out_w,
        xq, xk, xv, wq, wk, wv, wo);

    // merged Q/K/V projections; x = m-tile for XCD-affine A-panel reuse
    gemm_qkv<<<dim3(64, 8, 3), 256, 0, stream>>>(
        xq, wq, q_b, xk, wk, k_b, wv, xv, v_b, qh, kh, vt);

    // XCD-affine flash grid: x = bh (so XCD = bh%8), y = q-block (256 rows)
    flash_attn9<<<dim3(BB * HH, SS / 256), 512, 0, stream>>>(qh, kh, vt, attn);

    // out projection: 128x64 tiles, 1024 blocks = 4/CU
    gemm_out_n64<<<dim3(64, 16), 256, 0, stream>>>(attn, wo, out_b, (float*)d_out);
}